// Round 4
// baseline (4004.354 us; speedup 1.0000x reference)
//
#include <hip/hip_runtime.h>
#include <hip/hip_bf16.h>
#include <math.h>
#include <stdint.h>

// ViT config
#define VB   32
#define VS   197
#define VD   768
#define VNH  12
#define VDQ  64
#define VL   12
#define VMLP 3072
#define VC   1000
#define VP   256
#define VNPAT 196
#define VTOK (VB * VS)            // 6304
#define TOKD ((size_t)VTOK * VD)  // 4841472 floats

typedef __attribute__((ext_vector_type(4))) float f32x4;
typedef __attribute__((ext_vector_type(8))) short short8;

typedef __attribute__((address_space(1))) const unsigned int GU;
typedef __attribute__((address_space(3))) unsigned int LU;

__device__ __forceinline__ void gload_lds16(const void* g, void* l) {
    __builtin_amdgcn_global_load_lds((GU*)(uintptr_t)g, (LU*)(uintptr_t)l, 16, 0, 0);
}

// ---------------------------------------------------------------------------
// patchify: X (B,224,224) fp32 -> patches (B*196, 256) bf16
// ---------------------------------------------------------------------------
__global__ void patchify_k(const float* __restrict__ X, __hip_bfloat16* __restrict__ P) {
    int idx = blockIdx.x * 256 + threadIdx.x;
    const int total = VB * VNPAT * VP;
    if (idx >= total) return;
    int i  = idx & 255;
    int p  = (idx >> 8) % VNPAT;
    int b  = (idx >> 8) / VNPAT;
    int pr = p / 14, pc = p % 14;
    int a  = i >> 4, c2 = i & 15;
    P[idx] = __float2bfloat16(X[((size_t)b * 224 + pr * 16 + a) * 224 + pc * 16 + c2]);
}

// ---------------------------------------------------------------------------
// cls token + sinusoidal positional embeddings (x fp32)
// ---------------------------------------------------------------------------
__global__ void pos_cls_k(float* __restrict__ x, const float* __restrict__ cls) {
    size_t idx = (size_t)blockIdx.x * 256 + threadIdx.x;
    if (idx >= TOKD) return;
    int j = (int)(idx % VD);
    int s = (int)((idx / VD) % VS);
    float jj = (float)(j & ~1);
    float freq = expf(-(jj / (float)VD) * 9.2103403719761836f);
    float ang  = (float)s * freq;
    float pe   = (j & 1) ? cosf(ang) : sinf(ang);
    if (s == 0) x[idx] = cls[j] + pe;
    else        x[idx] += pe;
}

// ---------------------------------------------------------------------------
// LayerNorm: x fp32 -> y bf16. One block per token.
// ---------------------------------------------------------------------------
__global__ __launch_bounds__(256) void layernorm_k(
    const float* __restrict__ x, __hip_bfloat16* __restrict__ y,
    const float* __restrict__ g, const float* __restrict__ bta)
{
    int t = blockIdx.x;
    const float* xr = x + (size_t)t * VD;
    __hip_bfloat16* yr = y + (size_t)t * VD;
    int tid = threadIdx.x;
    float v[3];
    float s = 0.f;
    #pragma unroll
    for (int i = 0; i < 3; i++) { v[i] = xr[tid + i * 256]; s += v[i]; }
    __shared__ float red[8];
    #pragma unroll
    for (int off = 32; off; off >>= 1) s += __shfl_xor(s, off);
    int lane = tid & 63, w = tid >> 6;
    if (!lane) red[w] = s;
    __syncthreads();
    float mu = (red[0] + red[1] + red[2] + red[3]) * (1.f / VD);
    float s2 = 0.f;
    #pragma unroll
    for (int i = 0; i < 3; i++) { float d0 = v[i] - mu; s2 += d0 * d0; }
    #pragma unroll
    for (int off = 32; off; off >>= 1) s2 += __shfl_xor(s2, off);
    if (!lane) red[4 + w] = s2;
    __syncthreads();
    float var = (red[4] + red[5] + red[6] + red[7]) * (1.f / VD);
    float rs = rsqrtf(var + 1e-5f);
    #pragma unroll
    for (int i = 0; i < 3; i++) {
        int j = tid + i * 256;
        yr[j] = __float2bfloat16((v[i] - mu) * rs * g[j] + bta[j]);
    }
}

// ---------------------------------------------------------------------------
// Guarded transpose + bf16 convert: in (R,C) fp32 -> out (C,R) bf16.
// ---------------------------------------------------------------------------
__global__ __launch_bounds__(256) void tpose_k(
    const float* __restrict__ in, __hip_bfloat16* __restrict__ out, int R, int C)
{
    __shared__ float t[32][33];
    int c0 = blockIdx.x * 32, r0 = blockIdx.y * 32;
    int tc = threadIdx.x & 31, tr = threadIdx.x >> 5;
    #pragma unroll
    for (int p = 0; p < 4; p++) {
        int r = r0 + tr + p * 8;
        t[tr + p * 8][tc] = (r < R && c0 + tc < C) ? in[(size_t)r * C + c0 + tc] : 0.f;
    }
    __syncthreads();
    #pragma unroll
    for (int p = 0; p < 4; p++) {
        int c = c0 + tr + p * 8;
        if (c < C && r0 + tc < R)
            out[(size_t)c * R + r0 + tc] = __float2bfloat16(t[tc][tr + p * 8]);
    }
}

// ---------------------------------------------------------------------------
// Fused q/k/v weight transpose for one layer: (3 x 12 heads x 768 x 64) fp32
// -> out [2304][768] bf16 (rows m*768 + h*64 + e). grid (2, 24, 36).
// ---------------------------------------------------------------------------
__global__ __launch_bounds__(256) void qkvtp_k(
    const float* __restrict__ Wq, const float* __restrict__ Wk,
    const float* __restrict__ Wv, __hip_bfloat16* __restrict__ out)
{
    __shared__ float t[32][33];
    int z = blockIdx.z;
    int m = z / VNH, h = z % VNH;
    const float* src = (m == 0 ? Wq : m == 1 ? Wk : Wv) + (size_t)h * VD * VDQ;
    __hip_bfloat16* dst = out + ((size_t)m * VD + h * VDQ) * VD;
    int c0 = blockIdx.x * 32, r0 = blockIdx.y * 32;
    int tc = threadIdx.x & 31, tr = threadIdx.x >> 5;
    #pragma unroll
    for (int p = 0; p < 4; p++)
        t[tr + p * 8][tc] = src[(size_t)(r0 + tr + p * 8) * VDQ + c0 + tc];
    __syncthreads();
    #pragma unroll
    for (int p = 0; p < 4; p++)
        dst[(size_t)(c0 + tr + p * 8) * VD + r0 + tc] = __float2bfloat16(t[tc][tr + p * 8]);
}

// combined qkv bias for ALL layers: cb[l][2304]
__global__ void cball_k(const float* __restrict__ bq, const float* __restrict__ bk,
                        const float* __restrict__ bv, float* __restrict__ cb) {
    int idx = blockIdx.x * 256 + threadIdx.x;
    if (idx >= VL * 3 * VD) return;
    int l = idx / (3 * VD), n = idx % (3 * VD);
    int m = n / VD, wi = n % VD;
    const float* p = (m == 0) ? bq : (m == 1) ? bk : bv;
    cb[idx] = p[l * VD + wi];
}

// extract cls rows of x -> bf16 [32][768]
__global__ void cls_k(const float* __restrict__ x, __hip_bfloat16* __restrict__ out) {
    int idx = blockIdx.x * 256 + threadIdx.x;
    if (idx >= VB * VD) return;
    int b = idx / VD, d = idx % VD;
    out[idx] = __float2bfloat16(x[(size_t)b * VS * VD + d]);
}

// ---------------------------------------------------------------------------
// Pipelined bf16 MFMA GEMM: C[M,N] = A[M,K] @ BT[N,K]^T + bias
// BM=BN=128, BK=32 slabs, 4-deep LDS ring (64 KB), staging leads by 3 slabs,
// raw s_barrier + counted vmcnt(8) (never 0 in the main loop).
// Swizzle: 16B slot ^= (row>>1)&3 within 64B rows -> 2-way (free) ds_read.
// EPI: 0 = fp32 store w/ patch rowmap; 1 = bf16 store; 2 = fp32 accumulate;
//      3 = exact-GELU -> bf16; 4 = plain fp32 store. K mult of 32, K>=256.
// ---------------------------------------------------------------------------
template<int EPI>
__global__ __launch_bounds__(256) void bgemm2_k(
    const __hip_bfloat16* __restrict__ A,
    const __hip_bfloat16* __restrict__ BT,
    const float* __restrict__ bias,
    void* __restrict__ Co,
    int M, int K, int ldc, int Ncols)
{
    __shared__ short A_s[4][128][32];
    __shared__ short B_s[4][128][32];
    const int tid = threadIdx.x;
    const int w = tid >> 6, l = tid & 63;
    const int row0 = blockIdx.y * 128, col0 = blockIdx.x * 128;
    const int wm = (w >> 1) << 6, wn = (w & 1) << 6;
    const int Mm1 = M - 1;
    f32x4 acc[4][4] = {};

    const int fr = l & 15, g = l >> 4;
    const int wbase = tid & ~63;
    const int ns = K >> 5;

    // staging helper (inlined twice below): slab s -> ring buffer s&3
    #define STAGE_SLAB(s)                                                        \
    {                                                                            \
        const int k0s = (s) << 5;                                                \
        short* Asb = &A_s[(s) & 3][0][0];                                        \
        short* Bsb = &B_s[(s) & 3][0][0];                                        \
        _Pragma("unroll")                                                        \
        for (int q = 0; q < 2; q++) {                                            \
            int idx = tid + (q << 8);                                            \
            int r = idx >> 2;                                                    \
            int kofs = k0s + ((((idx & 3) ^ ((idx >> 3) & 3))) << 3);            \
            int dstb = (wbase + (q << 8)) << 4;                                  \
            gload_lds16(A + (size_t)min(row0 + r, Mm1) * K + kofs,               \
                        (char*)Asb + dstb);                                      \
            gload_lds16(BT + (size_t)(col0 + r) * K + kofs,                      \
                        (char*)Bsb + dstb);                                      \
        }                                                                        \
    }

    #define COMPUTE_SLAB(jj)                                                     \
    {                                                                            \
        const short* Asb = &A_s[(jj) & 3][0][0];                                 \
        const short* Bsb = &B_s[(jj) & 3][0][0];                                 \
        short8 av[4], bv[4];                                                     \
        _Pragma("unroll")                                                        \
        for (int i = 0; i < 4; i++) {                                            \
            int ar = wm + i * 16 + fr;                                           \
            av[i] = *(const short8*)((const char*)Asb + ar * 64 +                \
                                     ((g ^ ((ar >> 1) & 3)) << 4));              \
            int br = wn + i * 16 + fr;                                           \
            bv[i] = *(const short8*)((const char*)Bsb + br * 64 +                \
                                     ((g ^ ((br >> 1) & 3)) << 4));              \
        }                                                                        \
        _Pragma("unroll")                                                        \
        for (int i = 0; i < 4; i++)                                              \
            _Pragma("unroll")                                                    \
            for (int j2 = 0; j2 < 4; j2++)                                       \
                acc[i][j2] = __builtin_amdgcn_mfma_f32_16x16x32_bf16(            \
                    av[i], bv[j2], acc[i][j2], 0, 0, 0);                         \
    }

    // prologue: stage slabs 0,1,2
    STAGE_SLAB(0); STAGE_SLAB(1); STAGE_SLAB(2);
    asm volatile("s_waitcnt vmcnt(8)" ::: "memory");
    __builtin_amdgcn_s_barrier();

    for (int j = 0; j < ns - 3; j++) {
        STAGE_SLAB(j + 3);
        COMPUTE_SLAB(j);
        asm volatile("s_waitcnt vmcnt(8)" ::: "memory");
        __builtin_amdgcn_s_barrier();
    }
    asm volatile("s_waitcnt vmcnt(0)" ::: "memory");
    __builtin_amdgcn_s_barrier();
    COMPUTE_SLAB(ns - 3);
    COMPUTE_SLAB(ns - 2);
    COMPUTE_SLAB(ns - 1);

    #undef STAGE_SLAB
    #undef COMPUTE_SLAB

    const int rbase = row0 + wm + (g << 2);
    const int cbase = col0 + wn + fr;
    #pragma unroll
    for (int i = 0; i < 4; i++) {
        #pragma unroll
        for (int q = 0; q < 4; q++) {
            int rr = rbase + i * 16 + q;
            if (rr >= M) continue;
            #pragma unroll
            for (int j = 0; j < 4; j++) {
                int c = cbase + j * 16;
                if (c >= Ncols) continue;
                float v = acc[i][j][q] + bias[c];
                if (EPI == 0) {
                    int orow = rr + rr / VNPAT + 1;
                    ((float*)Co)[(size_t)orow * ldc + c] = v;
                } else if (EPI == 1) {
                    ((__hip_bfloat16*)Co)[(size_t)rr * ldc + c] = __float2bfloat16(v);
                } else if (EPI == 2) {
                    ((float*)Co)[(size_t)rr * ldc + c] += v;
                } else if (EPI == 3) {
                    float gl = 0.5f * v * (1.f + erff(v * 0.70710678118654752f));
                    ((__hip_bfloat16*)Co)[(size_t)rr * ldc + c] = __float2bfloat16(gl);
                } else {
                    ((float*)Co)[(size_t)rr * ldc + c] = v;
                }
            }
        }
    }
}

// ---------------------------------------------------------------------------
// MFMA attention (unchanged from round 3). One block per (b,h), 4 waves.
// ---------------------------------------------------------------------------
__device__ __forceinline__ int swz_idx(int row, int k) {
    return row * 256 + (((k >> 3) ^ (row & 7)) << 3) + (k & 7);
}
__device__ __forceinline__ unsigned pack_bf16(float a, float b) {
    __hip_bfloat16 x = __float2bfloat16(a), y = __float2bfloat16(b);
    unsigned short ux = *(unsigned short*)&x, uy = *(unsigned short*)&y;
    return (unsigned)ux | ((unsigned)uy << 16);
}

__global__ __launch_bounds__(256) void attn3_k(
    const __hip_bfloat16* __restrict__ qkv, __hip_bfloat16* __restrict__ o)
{
    __shared__ short V_t[64 * 256];
    __shared__ short P_s[4][16 * 256];
    const int bh = blockIdx.x;
    const int b = bh / VNH, h = bh % VNH;
    const int tid = threadIdx.x, w = tid >> 6, l = tid & 63;
    const int g = l >> 4, c16 = l & 15;

    const __hip_bfloat16* base = qkv + (size_t)(b * VS) * (3 * VD) + h * VDQ;

    {
        const __hip_bfloat16* vbase = base + 2 * VD;
        int t = tid & 31, e0 = (tid >> 5) * 8;
        #pragma unroll
        for (int it = 0; it < 7; it++) {
            int tt = it * 32 + t;
            if (tt < VS) {
                short8 vv = *(const short8*)(vbase + (size_t)tt * (3 * VD) + e0);
                #pragma unroll
                for (int j = 0; j < 8; j++) V_t[swz_idx(e0 + j, tt)] = vv[j];
            }
        }
        for (int idx = tid; idx < 64 * 27; idx += 256) {
            int e = idx / 27, k = 197 + idx % 27;
            V_t[swz_idx(e, k)] = 0;
        }
    }
    {
        unsigned* p0 = (unsigned*)&P_s[w][swz_idx(c16, 208 + g * 4)];
        p0[0] = 0; p0[1] = 0;
    }
    __syncthreads();

    for (int qt = w; qt < 13; qt += 4) {
        const int q0 = qt * 16;
        int qr = min(q0 + c16, VS - 1);
        const __hip_bfloat16* qp = base + (size_t)qr * (3 * VD) + g * 8;
        short8 qa0 = *(const short8*)(qp);
        short8 qa1 = *(const short8*)(qp + 32);

        f32x4 st[13];
        #pragma unroll
        for (int t = 0; t < 13; t++) {
            int kr = min(t * 16 + c16, VS - 1);
            const __hip_bfloat16* kp = base + VD + (size_t)kr * (3 * VD) + g * 8;
            short8 ka0 = *(const short8*)(kp);
            short8 ka1 = *(const short8*)(kp + 32);
            f32x4 z = {};
            z = __builtin_amdgcn_mfma_f32_16x16x32_bf16(ka0, qa0, z, 0, 0, 0);
            z = __builtin_amdgcn_mfma_f32_16x16x32_bf16(ka1, qa1, z, 0, 0, 0);
            st[t] = z;
        }
        #pragma unroll
        for (int t = 0; t < 13; t++) {
            #pragma unroll
            for (int r = 0; r < 4; r++) {
                float v = st[t][r] * 0.125f;
                if (t == 12 && (4 * g + r) >= 5) v = -3.0e38f;
                st[t][r] = v;
            }
        }
        float m = -3.0e38f;
        #pragma unroll
        for (int t = 0; t < 13; t++)
            #pragma unroll
            for (int r = 0; r < 4; r++) m = fmaxf(m, st[t][r]);
        m = fmaxf(m, __shfl_xor(m, 16));
        m = fmaxf(m, __shfl_xor(m, 32));
        float sum = 0.f;
        #pragma unroll
        for (int t = 0; t < 13; t++)
            #pragma unroll
            for (int r = 0; r < 4; r++) { float e = expf(st[t][r] - m); st[t][r] = e; sum += e; }
        sum += __shfl_xor(sum, 16);
        sum += __shfl_xor(sum, 32);
        float inv = 1.f / sum;
        #pragma unroll
        for (int t = 0; t < 13; t++) {
            int k0 = 16 * t + 4 * g;
            unsigned* pp = (unsigned*)&P_s[w][swz_idx(c16, k0)];
            pp[0] = pack_bf16(st[t][0] * inv, st[t][1] * inv);
            pp[1] = pack_bf16(st[t][2] * inv, st[t][3] * inv);
        }
        f32x4 acc[4] = {};
        #pragma unroll
        for (int ki = 0; ki < 7; ki++) {
            int k0 = ki * 32 + g * 8;
            short8 pa = *(const short8*)&P_s[w][swz_idx(c16, k0)];
            #pragma unroll
            for (int et = 0; et < 4; et++) {
                short8 vbf = *(const short8*)&V_t[swz_idx(et * 16 + c16, k0)];
                acc[et] = __builtin_amdgcn_mfma_f32_16x16x32_bf16(pa, vbf, acc[et], 0, 0, 0);
            }
        }
        #pragma unroll
        for (int et = 0; et < 4; et++) {
            #pragma unroll
            for (int r = 0; r < 4; r++) {
                int q = q0 + 4 * g + r;
                if (q < VS)
                    o[((size_t)(b * VS) + q) * VD + h * VDQ + et * 16 + c16] =
                        __float2bfloat16(acc[et][r]);
            }
        }
    }
}

// ---------------------------------------------------------------------------
extern "C" void kernel_launch(void* const* d_in, const int* in_sizes, int n_in,
                              void* d_out, int out_size, void* d_ws, size_t ws_size,
                              hipStream_t stream) {
    (void)in_sizes; (void)n_in; (void)out_size; (void)ws_size;
    const float* X       = (const float*)d_in[0];
    const float* patch_W = (const float*)d_in[1];
    const float* patch_b = (const float*)d_in[2];
    const float* cls_tok = (const float*)d_in[3];
    const float* ln1_g   = (const float*)d_in[4];
    const float* ln1_b   = (const float*)d_in[5];
    const float* Wq      = (const float*)d_in[6];
    const float* bq      = (const float*)d_in[7];
    const float* Wk      = (const float*)d_in[8];
    const float* bk      = (const float*)d_in[9];
    const float* Wv      = (const float*)d_in[10];
    const float* bv      = (const float*)d_in[11];
    const float* proj_W  = (const float*)d_in[12];
    const float* proj_b  = (const float*)d_in[13];
    const float* ln2_g   = (const float*)d_in[14];
    const float* ln2_b   = (const float*)d_in[15];
    const float* mlp_W1  = (const float*)d_in[16];
    const float* mlp_b1  = (const float*)d_in[17];
    const float* mlp_W2  = (const float*)d_in[18];
    const float* mlp_b2  = (const float*)d_in[19];
    const float* head_W  = (const float*)d_in[20];
    const float* head_b  = (const float*)d_in[21];

    char* ws = (char*)d_ws;
    float*          x   = (float*)ws;                             // 19.37 MB fp32
    __hip_bfloat16* tb  = (__hip_bfloat16*)(ws + 19365888);       // 9.68 MB bf16
    __hip_bfloat16* big = (__hip_bfloat16*)(ws + 29048832);       // 38.73 MB
    __hip_bfloat16* wT  = (__hip_bfloat16*)(ws + 67780608);       // 4.72 MB
    float*          cbA = (float*)(ws + 72499200);                // 110 KB (12x2304)

    // all-layer qkv bias concat (one launch)
    cball_k<<<(VL * 3 * VD + 255) / 256, 256, 0, stream>>>(bq, bk, bv, cbA);

    patchify_k<<<(VB * VNPAT * VP + 255) / 256, 256, 0, stream>>>(X, big);
    {
        dim3 g(VD / 32, VP / 32);
        tpose_k<<<g, 256, 0, stream>>>(patch_W, wT, VP, VD);
    }
    {
        dim3 g(VD / 128, VB * VNPAT / 128);
        bgemm2_k<0><<<g, 256, 0, stream>>>(big, wT, patch_b, x, VB * VNPAT, VP, VD, VD);
    }
    pos_cls_k<<<(unsigned)((TOKD + 255) / 256), 256, 0, stream>>>(x, cls_tok);

    const size_t WSZ = (size_t)VNH * VD * VDQ;
    for (int l = 0; l < VL; l++) {
        layernorm_k<<<VTOK, 256, 0, stream>>>(x, tb, ln1_g + l * VD, ln1_b + l * VD);

        {
            dim3 g(2, 24, 36);
            qkvtp_k<<<g, 256, 0, stream>>>(Wq + l * WSZ, Wk + l * WSZ, Wv + l * WSZ, wT);
        }
        {
            dim3 g(3 * VD / 128, (VTOK + 127) / 128);
            bgemm2_k<1><<<g, 256, 0, stream>>>(tb, wT, cbA + l * 3 * VD, big,
                                               VTOK, VD, 3 * VD, 3 * VD);
        }
        attn3_k<<<VB * VNH, 256, 0, stream>>>(big, tb);

        {
            dim3 gt(VD / 32, VD / 32);
            tpose_k<<<gt, 256, 0, stream>>>(proj_W + (size_t)l * VD * VD, wT, VD, VD);
            dim3 g(VD / 128, (VTOK + 127) / 128);
            bgemm2_k<2><<<g, 256, 0, stream>>>(tb, wT, proj_b + l * VD, x,
                                               VTOK, VD, VD, VD);
        }
        layernorm_k<<<VTOK, 256, 0, stream>>>(x, tb, ln2_g + l * VD, ln2_b + l * VD);
        {
            dim3 gt(VMLP / 32, VD / 32);
            tpose_k<<<gt, 256, 0, stream>>>(mlp_W1 + (size_t)l * VD * VMLP, wT, VD, VMLP);
            dim3 g(VMLP / 128, (VTOK + 127) / 128);
            bgemm2_k<3><<<g, 256, 0, stream>>>(tb, wT, mlp_b1 + l * VMLP, big,
                                               VTOK, VD, VMLP, VMLP);
        }
        {
            dim3 gt(VD / 32, VMLP / 32);
            tpose_k<<<gt, 256, 0, stream>>>(mlp_W2 + (size_t)l * VMLP * VD, wT, VMLP, VD);
            dim3 g(VD / 128, (VTOK + 127) / 128);
            bgemm2_k<2><<<g, 256, 0, stream>>>(big, wT, mlp_b2 + l * VD, x,
                                               VTOK, VMLP, VD, VD);
        }
    }
    // head: cls rows -> bf16, transpose head_W, MFMA GEMM (M=32, N=1000)
    cls_k<<<(VB * VD + 255) / 256, 256, 0, stream>>>(x, tb);
    {
        dim3 gt((VC + 31) / 32, VD / 32);
        tpose_k<<<gt, 256, 0, stream>>>(head_W, wT, VD, VC);
        dim3 g((VC + 127) / 128, 1);
        bgemm2_k<4><<<g, 256, 0, stream>>>(tb, wT, head_b, (float*)d_out,
                                           VB, VD, VC, VC);
    }
}